// Round 16
// baseline (108.047 us; speedup 1.0000x reference)
//
#include <hip/hip_runtime.h>

#define NVV   778
#define NSEG  16
#define SEGSZ 49
#define GRIDN 32
#define BATCH 128
#define NPTS  (NSEG * SEGSZ)           // 784
#define VOLSZ (GRIDN * GRIDN * GRIDN)  // 32768 floats = 128 KB
#define NBLK  256
#define VPB   16                        // volumes per persistent block

// clean 16/16 z-split: B0 = even pieces (slabs 0..15), B1 = odd pieces
// (slabs 16..31), 64 KB each. Piece p is written in phase p, tapped in
// phase p+1. 33 phases total (pieces 0..31 + final tap phase).
#define HF (16 * 1024)

typedef float f4 __attribute__((ext_vector_type(4)));

// ---- producer core: inline-asm nt loads (cannot be sunk by the
// compiler — R5/R6 failure mode) + manual counted vmcnt (T4). Each
// producer wave owns an 8 KB span: 8 x dwordx4 per phase. ----
#define ISSUE(S, SRC) { \
    const float* a_ = (SRC) + (wv << 11) + (lane << 2); \
    const float* b_ = a_ + 1024; \
    asm volatile("global_load_dwordx4 %0, %1, off nt"             : "=v"(S##0) : "v"(a_)); \
    asm volatile("global_load_dwordx4 %0, %1, off offset:1024 nt" : "=v"(S##1) : "v"(a_)); \
    asm volatile("global_load_dwordx4 %0, %1, off offset:2048 nt" : "=v"(S##2) : "v"(a_)); \
    asm volatile("global_load_dwordx4 %0, %1, off offset:3072 nt" : "=v"(S##3) : "v"(a_)); \
    asm volatile("global_load_dwordx4 %0, %1, off nt"             : "=v"(S##4) : "v"(b_)); \
    asm volatile("global_load_dwordx4 %0, %1, off offset:1024 nt" : "=v"(S##5) : "v"(b_)); \
    asm volatile("global_load_dwordx4 %0, %1, off offset:2048 nt" : "=v"(S##6) : "v"(b_)); \
    asm volatile("global_load_dwordx4 %0, %1, off offset:3072 nt" : "=v"(S##7) : "v"(b_)); \
}

// counted wait: 8 newer loads stay in flight; everything older retired.
#define WAITV8 { asm volatile("s_waitcnt vmcnt(8)" ::: "memory"); \
                 __builtin_amdgcn_sched_barrier(0); }
#define WAITV0 { asm volatile("s_waitcnt vmcnt(0)" ::: "memory"); \
                 __builtin_amdgcn_sched_barrier(0); }

#define WRITE(DST, S) { \
    float* d_ = (DST) + (wv << 11) + (lane << 2); \
    *(f4*)(d_ +    0) = S##0; \
    *(f4*)(d_ +  256) = S##1; \
    *(f4*)(d_ +  512) = S##2; \
    *(f4*)(d_ +  768) = S##3; \
    *(f4*)(d_ + 1024) = S##4; \
    *(f4*)(d_ + 1280) = S##5; \
    *(f4*)(d_ + 1536) = S##6; \
    *(f4*)(d_ + 1792) = S##7; }

// lgkm-only barrier: flushes ds_writes for cross-wave visibility but does
// NOT drain vmcnt — producer prefetch survives the barrier.
#define PBAR { asm volatile("s_waitcnt lgkmcnt(0)" ::: "memory"); \
               __builtin_amdgcn_s_barrier(); \
               asm volatile("" ::: "memory"); }

// 2x2 xy-taps within one z-slab
__device__ __forceinline__ float tapxy(const float* slab, int x0, int y0,
                                       float wx, float wy)
{
    float s = 0.f;
    #pragma unroll
    for (int dy = 0; dy < 2; ++dy) {
        int yy = y0 + dy;
        if (yy < 0 || yy >= GRIDN) continue;
        float wyv = dy ? wy : 1.f - wy;
        const float* row = slab + yy * GRIDN;
        #pragma unroll
        for (int dx = 0; dx < 2; ++dx) {
            int xx = x0 + dx;
            if (xx < 0 || xx >= GRIDN) continue;
            s += wyv * (dx ? wx : 1.f - wx) * row[xx];
        }
    }
    return s;
}

// Persistent: 256 blocks x 1024 threads (1 block/CU, ~128 KB LDS).
// Waves 0-7 = producers with a 2-deep register pipeline: phase p issues
// piece p+1's loads (asm, nt), waits vmcnt(8) (= piece p retired, piece
// p+1 in flight ACROSS the barrier), ds_writes piece p. Waves 8-15 =
// consumers tapping piece p-1. One deferred atomic per volume.
__global__ __launch_bounds__(1024, 4) void sample_kernel(
    const float* __restrict__ vertices, const int* __restrict__ seg,
    const float* __restrict__ phiR, const float* __restrict__ phiL,
    float* __restrict__ loss)
{
    __shared__ __align__(16) float B0[HF];
    __shared__ __align__(16) float B1[HF];
    __shared__ float4 sbox[VPB];
    __shared__ float wsum[8];

    const int tid  = threadIdx.x;
    const int bx   = blockIdx.x;
    const int k    = bx & (NSEG - 1);    // constant per block (256 % 16 == 0)
    const int wv   = tid >> 6;           // 0..7 producers, 8..15 consumers
    const int lane = tid & 63;
    const bool producer = (wv < 8);
    const int ct   = tid - 512;          // consumer thread id [0,512)

    auto phiPtr = [&](int it) {
        int vid  = bx + NBLK * it;
        int b    = (vid >> 4) & (BATCH - 1);
        int pass = vid >> 11;            // NSEG*BATCH = 2048
        return (pass == 0 ? phiR : phiL) + ((size_t)k * BATCH + b) * VOLSZ;
    };
    auto vertBase = [&](int it) {
        int vid  = bx + NBLK * it;
        int b    = (vid >> 4) & (BATCH - 1);
        int srcS = (vid >> 11) == 0 ? 1 : 0;   // pass0 samples LEFT verts
        return vertices + ((size_t)b * 2 + srcS) * NVV * 3;
    };
    auto bOf = [&](int it) { return (bx + NBLK * it) >> 4 & (BATCH - 1); };

    f4 X0, X1, X2, X3, X4, X5, X6, X7;   // producer reg set A
    f4 Y0, Y1, Y2, Y3, Y4, Y5, Y6, Y7;   // producer reg set B

    // ---- prologue ----
    int pvi1 = 0, pvi2 = 0;
    bool has2 = false;
    if (!producer) {
        pvi1 = seg[ct];
        has2 = (ct + 512) < NPTS;
        pvi2 = has2 ? seg[ct + 512] : 0;
    }

    // boxes: wave wv computes volume wv's box (all 16 waves)
    {
        int vidw    = bx + NBLK * wv;
        int bbw     = (vidw >> 4) & (BATCH - 1);
        int boxSide = ((vidw >> 11) == 0) ? 0 : 1;   // opposite of sampled
        bool bact   = lane < SEGSZ;
        int bvi     = bact ? seg[k * SEGSZ + lane] : 0;
        const float* bvp = vertices + (((size_t)bbw * 2 + boxSide) * NVV + bvi) * 3;
        float x = bvp[0], y = bvp[1], z = bvp[2];
        float mnx = bact ? x : 1e30f, mxx = bact ? x : -1e30f;
        float mny = bact ? y : 1e30f, mxy = bact ? y : -1e30f;
        float mnz = bact ? z : 1e30f, mxz = bact ? z : -1e30f;
        #pragma unroll
        for (int m = 32; m; m >>= 1) {
            mnx = fminf(mnx, __shfl_xor(mnx, m));
            mxx = fmaxf(mxx, __shfl_xor(mxx, m));
            mny = fminf(mny, __shfl_xor(mny, m));
            mxy = fmaxf(mxy, __shfl_xor(mxy, m));
            mnz = fminf(mnz, __shfl_xor(mnz, m));
            mxz = fmaxf(mxz, __shfl_xor(mxz, m));
        }
        if (lane == 0) {
            float ext = fmaxf(fmaxf(mxx - mnx, mxy - mny), mxz - mnz);
            sbox[wv] = make_float4(0.5f * (mnx + mxx), 0.5f * (mny + mxy),
                                   0.5f * (mnz + mxz), 1.0f / (0.55f * ext));
        }
    }

    // volume-0 point coords (consumers); producers issue piece 0 -> X
    float p1x = 0.f, p1y = 0.f, p1z = 0.f;
    float p2x = 0.f, p2y = 0.f, p2z = 0.f;
    if (producer) {
        ISSUE(X, phiPtr(0))
    } else {
        const float* vb = vertBase(0);
        p1x = vb[pvi1 * 3 + 0]; p1y = vb[pvi1 * 3 + 1]; p1z = vb[pvi1 * 3 + 2];
        if (has2) {
            p2x = vb[pvi2 * 3 + 0]; p2y = vb[pvi2 * 3 + 1]; p2z = vb[pvi2 * 3 + 2];
        }
    }
    PBAR   // sbox visible; X possibly still in flight

    // consumer per-volume state, carried across the phase pair
    bool a1 = false, a2 = false;
    int x1 = 0, y1 = 0, z1 = 0, x2 = 0, y2 = 0, z2 = 0;
    float w1x = 0.f, w1y = 0.f, w1z = 0.f, w2x = 0.f, w2y = 0.f, w2z = 0.f;
    float acc1 = 0.f, acc2 = 0.f;
    float n1x = 0.f, n1y = 0.f, n1z = 0.f;
    float n2x = 0.f, n2y = 0.f, n2z = 0.f;

    for (int h = 0; h <= 16; ++h) {
        // ===== even phase 2h: write piece 2h (h0(h)) -> B0; issue piece
        // 2h+1 -> Y; consumers tap piece 2h-1 (h1(h-1)) in B1 =====
        if (producer) {
            if (h <= 15) {
                ISSUE(Y, phiPtr(h) + HF)
                WAITV8              // X (piece 2h) retired; Y in flight
                WRITE(B0, X)
            }
        } else if (h >= 1) {
            if (a1 && z1 >= 15) {
                if (z1 >= 16)
                    acc1 += (1.f - w1z) * tapxy(B1 + (z1 - 16) * 1024, x1, y1, w1x, w1y);
                if (z1 <= 30)
                    acc1 += w1z * tapxy(B1 + (z1 - 15) * 1024, x1, y1, w1x, w1y);
            }
            if (a2 && z2 >= 15) {
                if (z2 >= 16)
                    acc2 += (1.f - w2z) * tapxy(B1 + (z2 - 16) * 1024, x2, y2, w2x, w2y);
                if (z2 <= 30)
                    acc2 += w2z * tapxy(B1 + (z2 - 15) * 1024, x2, y2, w2x, w2y);
            }
            float acc = acc1 + acc2;    // volume h-1 complete
            #pragma unroll
            for (int off = 32; off; off >>= 1)
                acc += __shfl_down(acc, off);
            if (lane == 0) wsum[wv - 8] = acc;
        }
        PBAR
        if (h == 16) break;

        // ===== odd phase 2h+1: write piece 2h+1 (h1(h)) -> B1; issue
        // piece 2h+2 -> X; consumers tap piece 2h (h0(h)) in B0 =====
        if (producer) {
            if (h <= 14) {
                ISSUE(X, phiPtr(h + 1))
                WAITV8              // Y (piece 2h+1) retired; X in flight
            } else {
                WAITV0              // tail: drain Y fully (once)
            }
            WRITE(B1, Y)
        } else {
            if (h >= 1 && ct == 0) {     // deferred atomic for volume h-1
                float tot = 0.f;
                #pragma unroll
                for (int i = 0; i < 8; ++i) tot += wsum[i];
                atomicAdd(loss + bOf(h - 1), tot * 0.25f);
            }
            // fresh state for volume h
            float4 b4 = sbox[h];
            float f1x = ((p1x - b4.x) * b4.w + 1.f) * 15.5f;
            float f1y = ((p1y - b4.y) * b4.w + 1.f) * 15.5f;
            float f1z = ((p1z - b4.z) * b4.w + 1.f) * 15.5f;
            float f2x = ((p2x - b4.x) * b4.w + 1.f) * 15.5f;
            float f2y = ((p2y - b4.y) * b4.w + 1.f) * 15.5f;
            float f2z = ((p2z - b4.z) * b4.w + 1.f) * 15.5f;
            a1 = (f1x > -1.f && f1x < 32.f && f1y > -1.f && f1y < 32.f &&
                  f1z > -1.f && f1z < 32.f);
            a2 = has2 && (f2x > -1.f && f2x < 32.f && f2y > -1.f && f2y < 32.f &&
                  f2z > -1.f && f2z < 32.f);
            float x1f = floorf(f1x), y1f = floorf(f1y), z1f = floorf(f1z);
            float x2f = floorf(f2x), y2f = floorf(f2y), z2f = floorf(f2z);
            w1x = f1x - x1f; w1y = f1y - y1f; w1z = f1z - z1f;
            w2x = f2x - x2f; w2y = f2y - y2f; w2z = f2z - z2f;
            x1 = (int)x1f; y1 = (int)y1f; z1 = (int)z1f;
            x2 = (int)x2f; y2 = (int)y2f; z2 = (int)z2f;
            acc1 = 0.f; acc2 = 0.f;
            if (a1 && z1 <= 15) {
                if (z1 >= 0)
                    acc1 += (1.f - w1z) * tapxy(B0 + z1 * 1024, x1, y1, w1x, w1y);
                if (z1 <= 14)
                    acc1 += w1z * tapxy(B0 + (z1 + 1) * 1024, x1, y1, w1x, w1y);
            }
            if (a2 && z2 <= 15) {
                if (z2 >= 0)
                    acc2 += (1.f - w2z) * tapxy(B0 + z2 * 1024, x2, y2, w2x, w2y);
                if (z2 <= 14)
                    acc2 += w2z * tapxy(B0 + (z2 + 1) * 1024, x2, y2, w2x, w2y);
            }
            if (h <= 14) {               // coords for volume h+1
                const float* vb = vertBase(h + 1);
                n1x = vb[pvi1 * 3 + 0]; n1y = vb[pvi1 * 3 + 1]; n1z = vb[pvi1 * 3 + 2];
                if (has2) {
                    n2x = vb[pvi2 * 3 + 0]; n2y = vb[pvi2 * 3 + 1]; n2z = vb[pvi2 * 3 + 2];
                }
            }
            p1x = n1x; p1y = n1y; p1z = n1z;
            p2x = n2x; p2y = n2y; p2z = n2z;
        }
        PBAR
    }

    // final volume (15): wsum written in even phase h=16
    if (!producer && ct == 0) {
        float tot = 0.f;
        #pragma unroll
        for (int i = 0; i < 8; ++i) tot += wsum[i];
        atomicAdd(loss + bOf(VPB - 1), tot * 0.25f);
    }
}

extern "C" void kernel_launch(void* const* d_in, const int* in_sizes, int n_in,
                              void* d_out, int out_size, void* d_ws, size_t ws_size,
                              hipStream_t stream) {
    const float* vertices = (const float*)d_in[0];
    const float* phiR     = (const float*)d_in[1];
    const float* phiL     = (const float*)d_in[2];
    const int*   seg      = (const int*)d_in[3];
    float* loss = (float*)d_out;

    hipMemsetAsync(d_out, 0, (size_t)out_size * sizeof(float), stream);

    sample_kernel<<<NBLK, 1024, 0, stream>>>(vertices, seg, phiR, phiL, loss);
}

// Round 17
// 101.191 us; speedup vs baseline: 1.0678x; 1.0678x over previous
//
#include <hip/hip_runtime.h>

#define NVV   778
#define NSEG  16
#define SEGSZ 49
#define GRIDN 32
#define BATCH 128
#define NPTS  784
#define VOLSZ (GRIDN * GRIDN * GRIDN)  // 32768 floats = 128 KB
#define NBLK  512                       // 2 blocks/CU
#define VPB   8                         // volumes per block
#define PFLT  8192                      // floats per piece (8 slabs, 32 KB)

typedef float f4v __attribute__((ext_vector_type(4)));
#define NTLD(p) __builtin_nontemporal_load((const f4v*)(p))

// 32 KB piece staged by 4 producer waves (wv 0-3): 8 KB/wave, 8 x dwordx4
// nt loads (no L2/L3 allocation — R15's proven +5% win).
#define STAGE(DST, SRC) { \
    const float* s_ = (SRC) + (wv << 11) + (lane << 2); \
    float*       d_ = (DST) + (wv << 11) + (lane << 2); \
    f4v c0 = NTLD(s_ + 0 * 256); \
    f4v c1 = NTLD(s_ + 1 * 256); \
    f4v c2 = NTLD(s_ + 2 * 256); \
    f4v c3 = NTLD(s_ + 3 * 256); \
    f4v c4 = NTLD(s_ + 4 * 256); \
    f4v c5 = NTLD(s_ + 5 * 256); \
    f4v c6 = NTLD(s_ + 6 * 256); \
    f4v c7 = NTLD(s_ + 7 * 256); \
    *(f4v*)(d_ + 0 * 256) = c0; \
    *(f4v*)(d_ + 1 * 256) = c1; \
    *(f4v*)(d_ + 2 * 256) = c2; \
    *(f4v*)(d_ + 3 * 256) = c3; \
    *(f4v*)(d_ + 4 * 256) = c4; \
    *(f4v*)(d_ + 5 * 256) = c5; \
    *(f4v*)(d_ + 6 * 256) = c6; \
    *(f4v*)(d_ + 7 * 256) = c7; }

// 2x2 xy-taps within one z-slab
__device__ __forceinline__ float tapxy(const float* slab, int x0, int y0,
                                       float wx, float wy)
{
    float s = 0.f;
    #pragma unroll
    for (int dy = 0; dy < 2; ++dy) {
        int yy = y0 + dy;
        if (yy < 0 || yy >= GRIDN) continue;
        float wyv = dy ? wy : 1.f - wy;
        const float* row = slab + yy * GRIDN;
        #pragma unroll
        for (int dx = 0; dx < 2; ++dx) {
            int xx = x0 + dx;
            if (xx < 0 || xx >= GRIDN) continue;
            s += wyv * (dx ? wx : 1.f - wx) * row[xx];
        }
    }
    return s;
}

// point J's taps that land in piece Q (slab s belongs to piece s>>3)
#define TAP1(Q, BASE, J) \
    if (a##J) { \
        if (z##J >= 0 && (z##J >> 3) == (Q)) \
            acc##J += (1.f - w##J##z) * tapxy((BASE) + (z##J - 8 * (Q)) * 1024, x##J, y##J, w##J##x, w##J##y); \
        if ((z##J + 1) <= 31 && ((z##J + 1) >> 3) == (Q)) \
            acc##J += w##J##z * tapxy((BASE) + (z##J + 1 - 8 * (Q)) * 1024, x##J, y##J, w##J##x, w##J##y); \
    }
#define TAPALL(Q, BASE) \
    TAP1(Q, BASE, 1) TAP1(Q, BASE, 2) TAP1(Q, BASE, 3) \
    if (has4) { TAP1(Q, BASE, 4) }

#define SETUP(J, PX, PY, PZ) { \
    float fx = ((PX) - b4.x) * b4.w * 15.5f + 15.5f; \
    float fy = ((PY) - b4.y) * b4.w * 15.5f + 15.5f; \
    float fz = ((PZ) - b4.z) * b4.w * 15.5f + 15.5f; \
    a##J = (fx > -1.f && fx < 32.f && fy > -1.f && fy < 32.f && \
            fz > -1.f && fz < 32.f); \
    float xf = floorf(fx), yf = floorf(fy), zf = floorf(fz); \
    w##J##x = fx - xf; w##J##y = fy - yf; w##J##z = fz - zf; \
    x##J = (int)xf; y##J = (int)yf; z##J = (int)zf; acc##J = 0.f; }

// Persistent: 512 blocks x 512 threads -> 2 independent blocks per CU
// (~66 KB LDS each). Cross-block TLP is the latency hider: while one
// block drains its producers' vmcnt at a barrier, the co-resident block's
// producers keep streaming. Intra-block: simple proven R15 structure —
// waves 0-3 stage a 32 KB piece (nt loads), waves 4-7 tap the previous
// piece, plain __syncthreads. 4 phases/volume, 8 volumes/block. One
// deferred atomic per volume (R10 lesson).
__global__ __launch_bounds__(512, 4) void sample_kernel(
    const float* __restrict__ vertices, const int* __restrict__ seg,
    const float* __restrict__ phiR, const float* __restrict__ phiL,
    float* __restrict__ loss)
{
    __shared__ __align__(16) float P0[PFLT];
    __shared__ __align__(16) float P1[PFLT];
    __shared__ float4 sbox[VPB];
    __shared__ float wsum[4];

    const int tid  = threadIdx.x;
    const int bx   = blockIdx.x;
    const int k    = bx & (NSEG - 1);    // constant per block (512 % 16 == 0)
    const int wv   = tid >> 6;           // 0..3 producers, 4..7 consumers
    const int lane = tid & 63;
    const bool producer = (wv < 4);
    const int ct   = tid - 256;          // consumer thread id [0,256)

    auto phiPtr = [&](int it) {
        int vid  = bx + NBLK * it;
        int b    = (vid >> 4) & (BATCH - 1);
        int pass = vid >> 11;            // NSEG*BATCH = 2048
        return (pass == 0 ? phiR : phiL) + ((size_t)k * BATCH + b) * VOLSZ;
    };
    auto vertBase = [&](int it) {
        int vid  = bx + NBLK * it;
        int b    = (vid >> 4) & (BATCH - 1);
        int srcS = (vid >> 11) == 0 ? 1 : 0;   // pass0 samples LEFT verts
        return vertices + ((size_t)b * 2 + srcS) * NVV * 3;
    };
    auto bOf = [&](int it) { return ((bx + NBLK * it) >> 4) & (BATCH - 1); };

    // ---- prologue ----
    int pvi1 = 0, pvi2 = 0, pvi3 = 0, pvi4 = 0;
    bool has4 = false;
    if (!producer) {
        pvi1 = seg[ct];
        pvi2 = seg[ct + 256];
        pvi3 = seg[ct + 512];
        has4 = (ct + 768) < NPTS;        // ct < 16
        pvi4 = has4 ? seg[ct + 768] : 0;
    }

    // boxes: wave wv computes volume wv's box (8 waves = VPB)
    {
        int vidw    = bx + NBLK * wv;
        int bbw     = (vidw >> 4) & (BATCH - 1);
        int boxSide = ((vidw >> 11) == 0) ? 0 : 1;   // opposite of sampled
        bool bact   = lane < SEGSZ;
        int bvi     = bact ? seg[k * SEGSZ + lane] : 0;
        const float* bvp = vertices + (((size_t)bbw * 2 + boxSide) * NVV + bvi) * 3;
        float x = bvp[0], y = bvp[1], z = bvp[2];
        float mnx = bact ? x : 1e30f, mxx = bact ? x : -1e30f;
        float mny = bact ? y : 1e30f, mxy = bact ? y : -1e30f;
        float mnz = bact ? z : 1e30f, mxz = bact ? z : -1e30f;
        #pragma unroll
        for (int m = 32; m; m >>= 1) {
            mnx = fminf(mnx, __shfl_xor(mnx, m));
            mxx = fmaxf(mxx, __shfl_xor(mxx, m));
            mny = fminf(mny, __shfl_xor(mny, m));
            mxy = fmaxf(mxy, __shfl_xor(mxy, m));
            mnz = fminf(mnz, __shfl_xor(mnz, m));
            mxz = fmaxf(mxz, __shfl_xor(mxz, m));
        }
        if (lane == 0) {
            float ext = fmaxf(fmaxf(mxx - mnx, mxy - mny), mxz - mnz);
            sbox[wv] = make_float4(0.5f * (mnx + mxx), 0.5f * (mny + mxy),
                                   0.5f * (mnz + mxz), 1.0f / (0.55f * ext));
        }
    }

    // volume-0 coords (consumers); producers stage piece 0 -> P0
    float p1x = 0.f, p1y = 0.f, p1z = 0.f, p2x = 0.f, p2y = 0.f, p2z = 0.f;
    float p3x = 0.f, p3y = 0.f, p3z = 0.f, p4x = 0.f, p4y = 0.f, p4z = 0.f;
    if (producer) {
        STAGE(P0, phiPtr(0))
    } else {
        const float* vb = vertBase(0);
        p1x = vb[pvi1 * 3]; p1y = vb[pvi1 * 3 + 1]; p1z = vb[pvi1 * 3 + 2];
        p2x = vb[pvi2 * 3]; p2y = vb[pvi2 * 3 + 1]; p2z = vb[pvi2 * 3 + 2];
        p3x = vb[pvi3 * 3]; p3y = vb[pvi3 * 3 + 1]; p3z = vb[pvi3 * 3 + 2];
        if (has4) {
            p4x = vb[pvi4 * 3]; p4y = vb[pvi4 * 3 + 1]; p4z = vb[pvi4 * 3 + 2];
        }
    }
    __syncthreads();   // P0 resident; sbox visible

    float n1x = 0.f, n1y = 0.f, n1z = 0.f, n2x = 0.f, n2y = 0.f, n2z = 0.f;
    float n3x = 0.f, n3y = 0.f, n3z = 0.f, n4x = 0.f, n4y = 0.f, n4z = 0.f;

    for (int v = 0; v < VPB; ++v) {
        const bool more = (v + 1 < VPB);
        bool a1 = false, a2 = false, a3 = false, a4 = false;
        int x1, y1, z1, x2, y2, z2, x3, y3, z3, x4, y4, z4;
        float w1x, w1y, w1z, w2x, w2y, w2z, w3x, w3y, w3z, w4x, w4y, w4z;
        float acc1 = 0.f, acc2 = 0.f, acc3 = 0.f, acc4 = 0.f;

        // ===== phase 0: stage piece 1 -> P1; tap piece 0 in P0 =====
        if (producer) {
            STAGE(P1, phiPtr(v) + PFLT)
        } else {
            if (v > 0 && ct == 0) {      // deferred atomic for volume v-1
                float tot = wsum[0] + wsum[1] + wsum[2] + wsum[3];
                atomicAdd(loss + bOf(v - 1), tot * 0.25f);
            }
            float4 b4 = sbox[v];
            SETUP(1, p1x, p1y, p1z)
            SETUP(2, p2x, p2y, p2z)
            SETUP(3, p3x, p3y, p3z)
            if (has4) { SETUP(4, p4x, p4y, p4z) }
            TAPALL(0, P0)
        }
        __syncthreads();

        // ===== phase 1: stage piece 2 -> P0; tap piece 1 in P1 =====
        if (producer) {
            STAGE(P0, phiPtr(v) + 2 * PFLT)
        } else {
            TAPALL(1, P1)
        }
        __syncthreads();

        // ===== phase 2: stage piece 3 -> P1; tap piece 2 in P0 =====
        if (producer) {
            STAGE(P1, phiPtr(v) + 3 * PFLT)
        } else {
            TAPALL(2, P0)
            if (more) {                  // next volume's coords (scattered)
                const float* vb = vertBase(v + 1);
                n1x = vb[pvi1 * 3]; n1y = vb[pvi1 * 3 + 1]; n1z = vb[pvi1 * 3 + 2];
                n2x = vb[pvi2 * 3]; n2y = vb[pvi2 * 3 + 1]; n2z = vb[pvi2 * 3 + 2];
                n3x = vb[pvi3 * 3]; n3y = vb[pvi3 * 3 + 1]; n3z = vb[pvi3 * 3 + 2];
                if (has4) {
                    n4x = vb[pvi4 * 3]; n4y = vb[pvi4 * 3 + 1]; n4z = vb[pvi4 * 3 + 2];
                }
            }
        }
        __syncthreads();

        // ===== phase 3: stage piece 0 of v+1 -> P0; tap piece 3 in P1 ==
        if (producer) {
            if (more) { STAGE(P0, phiPtr(v + 1)) }
        } else {
            TAPALL(3, P1)
            float acc = acc1 + acc2 + acc3 + acc4;
            #pragma unroll
            for (int off = 32; off; off >>= 1)
                acc += __shfl_down(acc, off);
            if (lane == 0) wsum[wv - 4] = acc;
        }
        __syncthreads();   // P0 (next) resident; P1 consumed; wsum visible

        p1x = n1x; p1y = n1y; p1z = n1z; p2x = n2x; p2y = n2y; p2z = n2z;
        p3x = n3x; p3y = n3y; p3z = n3z; p4x = n4x; p4y = n4y; p4z = n4z;
    }

    // final volume's atomic
    if (!producer && ct == 0) {
        float tot = wsum[0] + wsum[1] + wsum[2] + wsum[3];
        atomicAdd(loss + bOf(VPB - 1), tot * 0.25f);
    }
}

extern "C" void kernel_launch(void* const* d_in, const int* in_sizes, int n_in,
                              void* d_out, int out_size, void* d_ws, size_t ws_size,
                              hipStream_t stream) {
    const float* vertices = (const float*)d_in[0];
    const float* phiR     = (const float*)d_in[1];
    const float* phiL     = (const float*)d_in[2];
    const int*   seg      = (const int*)d_in[3];
    float* loss = (float*)d_out;

    hipMemsetAsync(d_out, 0, (size_t)out_size * sizeof(float), stream);

    sample_kernel<<<NBLK, 512, 0, stream>>>(vertices, seg, phiR, phiL, loss);
}